// Round 10
// baseline (106.189 us; speedup 1.0000x reference)
//
#include <hip/hip_runtime.h>
#include <hip/hip_bf16.h>

// B=4, C=64, O=64, H=W=128, K=3, KK=9, PAD=1
// MFMA 16x16x32 bf16: A[m=lane&15][k=(lane>>4)*8+j], B[n=lane&15][k=...],
// C/D: col(n)=lane&15, row(m)=(lane>>4)*4+reg
// kappa = s*32 + q*8 + j  ->  tap = s>>1, c = (s&1)*32 + q*8 + j
//
// Round-10: (1) transpose: float4 global loads (was 32 scalar f32/thread);
// (2) deform sampling: 4 lanes/pixel (16ch each, 2x uint4 per corner) -> each
// coord/weight computation serves 16 px per wave-instr (was 8) = half the
// coordinate VALU; same load depth (16 uint4 in flight per 2-tap chunk).
// Evidence: r7 deform VGPR=40 MfmaUtil 6% VALUBusy 35% HBM 6% (latency+VALU);
// r8/r9 ILP fixes -2.4/-3.7 us. Timed region carries a ~44.5us harness fill.
//
// ws layout (bytes):
//   xBp  [4][130][130][64] bf16 : ofs 0        (8.65 MB zero-halo padded NHWC bf16 of x)
//   Wb   [4][18][64][8]   bf16  : ofs 8652800  (deform weight B-frags)
//   OWb  [2][18][64][8]   bf16  : ofs 8726528  (offset_w B-frags)

typedef short short8 __attribute__((ext_vector_type(8)));
typedef float f32x4 __attribute__((ext_vector_type(4)));

static __device__ inline short bf16s(float f) {
    __hip_bfloat16 h = __float2bfloat16(f);
    return *(short*)&h;
}
static __device__ inline float lo2f(unsigned u) { return __uint_as_float(u << 16); }
static __device__ inline float hi2f(unsigned u) { return __uint_as_float(u & 0xffff0000u); }

// ---------------------------------------------------------------- fused prep + NCHW->padded-NHWC-bf16
// grid = 736: blocks 0..519 transpose (XCD-swizzled), 520..735 prep fragment packing.
__global__ void prep_transpose_kernel(const float* __restrict__ x,
                                      __hip_bfloat16* __restrict__ xBp,
                                      const float* __restrict__ offset_w, // [18][64][9]
                                      const float* __restrict__ weight,   // [64][64][9]
                                      __hip_bfloat16* __restrict__ Wb,    // [4][18][64][8]
                                      __hip_bfloat16* __restrict__ OWb)   // [2][18][64][8]
{
    __shared__ __align__(16) float lds[128 * 65];
    int raw = blockIdx.x;
    int t = threadIdx.x;

    if (raw >= 520) {                   // ---- prep path
        int id = (raw - 520) * 256 + t;
        if (id < 36864) {
            int j    = id & 7;
            int lane = (id >> 3) & 63;
            int id3  = id >> 9;
            int s    = id3 % 18;
            int otile = id3 / 18;
            int n = lane & 15, q = lane >> 4;
            int kap = s * 32 + q * 8 + j;      // kappa = k*64 + c
            int k = kap >> 6, c = kap & 63;
            int o = otile * 16 + n;
            Wb[id] = __float2bfloat16(weight[(o * 64 + c) * 9 + k]);
        }
        int id2 = id - 36864;
        if (id2 >= 0 && id2 < 18432) {
            int j    = id2 & 7;
            int lane = (id2 >> 3) & 63;
            int id3  = id2 >> 9;
            int s    = id3 % 18;
            int ntile = id3 / 18;
            int n = lane & 15, q = lane >> 4;
            int kap = s * 32 + q * 8 + j;
            int k = kap >> 6, c = kap & 63;
            int o = ntile * 16 + n;
            float v = (o < 18) ? offset_w[(o * 64 + c) * 9 + k] : 0.0f;
            OWb[id2] = __float2bfloat16(v);
        }
        return;
    }

    // ---- transpose path (XCD swizzle: 520 = 8*65)
    int blk = (raw & 7) * 65 + (raw >> 3);   // b*130 + r
    int b = blk / 130, r = blk - b * 130;
    unsigned* rowp = (unsigned*)(xBp + (size_t)(b * 130 + r) * 130 * 64); // 4160 dwords per row
    if (r == 0 || r == 129) {           // full zero row (halo)
        uint4 z = {0u, 0u, 0u, 0u};
        for (int i = 0; i < 5; ++i) {
            int e = i * 256 + t;
            if (e < 1040) ((uint4*)rowp)[e] = z;
        }
        return;
    }
    int h = r - 1;
    // load 64c x 128w floats as float4 along w: 2048 float4, 8 per thread
    const float4* x4 = (const float4*)x;
    size_t base4 = (size_t)b * 262144 + (size_t)h * 32;  // + c*4096 + w4
#pragma unroll
    for (int i = 0; i < 8; ++i) {
        int idx = i * 256 + t;          // idx = c*32 + w4
        int c = idx >> 5, w4 = idx & 31;
        float4 v = x4[base4 + (size_t)c * 4096 + w4];
        int wb = w4 * 4;
        lds[(wb + 0) * 65 + c] = v.x;
        lds[(wb + 1) * 65 + c] = v.y;
        lds[(wb + 2) * 65 + c] = v.z;
        lds[(wb + 3) * 65 + c] = v.w;
    }
    __syncthreads();
    unsigned* dst = rowp + 32;          // col 1 (each col = 64 shorts = 32 dwords)
    for (int i = 0; i < 16; ++i) {
        int L = i * 256 + t;            // L = ww*32 + c2
        int ww = L >> 5, c2 = L & 31;
        float f0 = lds[ww * 65 + c2 * 2];
        float f1 = lds[ww * 65 + c2 * 2 + 1];
        unsigned pk = ((unsigned)bf16s(f0) & 0xffffu) | ((unsigned)bf16s(f1) << 16);
        dst[L] = pk;
    }
    if (t < 64) {                       // zero halo cols 0 and 129
        int col = (t >> 5) * 129;
        rowp[col * 32 + (t & 31)] = 0u;
    }
}

// ---------------------------------------------------------------- phase-4 sampling helper
// Lane owns 16 channels (c16*16..+15) of pixel p; taps K0..K1-1.
// Loop 1 issues ALL corner loads (2x uint4 per corner, statically-indexed reg
// arrays -> no scratch), loop 2 consumes. Zero-halo: clamp to [-1,128].
template<int K0, int K1>
static __device__ inline void sample_taps16(const __hip_bfloat16* __restrict__ xb16,
                                            const float* __restrict__ offL,
                                            short* __restrict__ sampB,
                                            int h, int w0, int p, int c16)
{
    constexpr int NT = K1 - K0;
    float wa[NT], wb_[NT], wc[NT], wd[NT];
    uint4 a0[NT], a1[NT], b0[NT], b1[NT], c0[NT], c1[NT], d0[NT], d1[NT];
#pragma unroll
    for (int i = 0; i < NT; ++i) {
        int k = K0 + i;
        float offy = offL[(2 * k) * 16 + p];
        float offx = offL[(2 * k + 1) * 16 + p];
        float py = (float)(h - 1 + (k / 3)) + offy;
        float px = (float)(w0 + p - 1 + (k % 3)) + offx;
        float y0f = floorf(py), x0f = floorf(px);
        float wy1 = py - y0f, wx1 = px - x0f;
        float wy0 = 1.0f - wy1, wx0 = 1.0f - wx1;
        int iy = (int)y0f, ix = (int)x0f;
        int iy0 = min(max(iy, -1), 128);
        int ix0 = min(max(ix, -1), 128);
        int iy1 = min(max(iy + 1, -1), 128);
        int ix1 = min(max(ix + 1, -1), 128);
        int rb0 = iy0 * 130, rb1 = iy1 * 130;
        const __hip_bfloat16* p00 = xb16 + (rb0 + ix0) * 64;
        const __hip_bfloat16* p01 = xb16 + (rb0 + ix1) * 64;
        const __hip_bfloat16* p10 = xb16 + (rb1 + ix0) * 64;
        const __hip_bfloat16* p11 = xb16 + (rb1 + ix1) * 64;
        a0[i] = *(const uint4*)(p00);  a1[i] = *(const uint4*)(p00 + 8);
        b0[i] = *(const uint4*)(p01);  b1[i] = *(const uint4*)(p01 + 8);
        c0[i] = *(const uint4*)(p10);  c1[i] = *(const uint4*)(p10 + 8);
        d0[i] = *(const uint4*)(p11);  d1[i] = *(const uint4*)(p11 + 8);
        wa[i] = wy0 * wx0;
        wb_[i] = wy0 * wx1;
        wc[i] = wy1 * wx0;
        wd[i] = wy1 * wx1;
    }
#pragma unroll
    for (int i = 0; i < NT; ++i) {
        int k = K0 + i;
        int s = 2 * k + (c16 >> 1);
        int base = (s * 16 + p) * 40 + (c16 & 1) * 16;
        short8 pk;
#define S1(idx, comp, EXT, R) \
        pk[idx] = bf16s(fmaf(wd[i], EXT(d##R[i].comp), fmaf(wc[i], EXT(c##R[i].comp), \
                  fmaf(wb_[i], EXT(b##R[i].comp), wa[i] * EXT(a##R[i].comp)))));
        S1(0, x, lo2f, 0) S1(1, x, hi2f, 0) S1(2, y, lo2f, 0) S1(3, y, hi2f, 0)
        S1(4, z, lo2f, 0) S1(5, z, hi2f, 0) S1(6, w, lo2f, 0) S1(7, w, hi2f, 0)
        *(short8*)&sampB[base] = pk;
        S1(0, x, lo2f, 1) S1(1, x, hi2f, 1) S1(2, y, lo2f, 1) S1(3, y, hi2f, 1)
        S1(4, z, lo2f, 1) S1(5, z, hi2f, 1) S1(6, w, lo2f, 1) S1(7, w, hi2f, 1)
        *(short8*)&sampB[base + 8] = pk;
#undef S1
    }
}

// ---------------------------------------------------------------- fused offconv + sampling + deform conv
// block = 16x1 row tile; 4 waves; grid = 4096 (XCD-swizzled: 8*512)
// LDS = sampB 23040 (patch[54][80] aliases its head) + offL 1152 = 24192 B
// launch_bounds(256,4): VGPR cap 128 so a full gather tap-batch stays in flight.
__global__ __launch_bounds__(256, 4) void deform_kernel(
    const __hip_bfloat16* __restrict__ xBp, // [4][130][130][64] padded NHWC bf16
    const __hip_bfloat16* __restrict__ Wb,  // [4][18][64][8]
    const __hip_bfloat16* __restrict__ OWb, // [2][18][64][8]
    const float* __restrict__ offset_b,     // [18]
    const float* __restrict__ bias,         // [64]
    float* __restrict__ out)                // [4][64][128][128] NCHW
{
    __shared__ __align__(16) short sampB[18 * 16 * 40];  // 23040 B
    __shared__ __align__(16) float offL[288];            // [o][p] (separate — NOT aliased)

    int t = threadIdx.x, wv = t >> 6, lane = t & 63;
    int bid = (blockIdx.x & 7) * 512 + (blockIdx.x >> 3); // XCD swizzle: contiguous (b,h) per XCD
    int b  = bid >> 10;
    int h  = (bid >> 3) & 127;
    int w0 = (bid & 7) << 4;

    short* patch = sampB;            // [54 px][80 shorts]; px = row*18+col
                                     // rows = padded h..h+2, cols = padded w0..w0+17

    // ---- phase 1: stage 3x18x64 patch bf16 — branchless (halo is pre-zeroed), 16-B chunks
    {
#pragma unroll
        for (int i = 0; i < 2; ++i) {
            int e = i * 256 + t;            // 54*8 = 432 chunks of 16 B
            if (e < 432) {
                int px = e >> 3, part = e & 7;
                int row = px / 18, col = px - row * 18;
                const uint4* src = (const uint4*)(xBp +
                    ((size_t)((b * 130 + h + row) * 130) + w0 + col) * 64 + part * 8);
                *(uint4*)&patch[px * 80 + part * 8] = *src;
            }
        }
    }
    __syncthreads();

    // ---- phase 2: offset conv via MFMA (waves 0,1; o = wv*16+n; pixel p = q*4+reg)
    if (wv < 2) {
        int n = lane & 15, q = lane >> 4;
        const short8* Bw = (const short8*)OWb + (wv * 18) * 64 + lane;
        f32x4 acc = {0.f, 0.f, 0.f, 0.f};
#pragma unroll
        for (int s = 0; s < 18; ++s) {
            int k = s >> 1;
            int ky = k / 3, kx = k - ky * 3;
            int pix = ky * 18 + n + kx;
            const short8 a = *(const short8*)&patch[pix * 80 + (s & 1) * 32 + q * 8];
            acc = __builtin_amdgcn_mfma_f32_16x16x32_bf16(a, Bw[s * 64], acc, 0, 0, 0);
        }
        int o = wv * 16 + n;
        if (o < 18) {
            float bo = offset_b[o];
#pragma unroll
            for (int r = 0; r < 4; ++r)
                offL[o * 16 + q * 4 + r] = acc[r] + bo;
        }
    }
    __syncthreads();

    // ---- phase 4: sampling; 4 lanes/pixel (lane owns 16 channels), taps split over waves
    // wave 0: taps 0-1, wave 1: taps 2-3, wave 2: taps 4-5, wave 3: taps 6-8 (2+1 chunks).
    // p = lane>>2 covers all 16 px per wave. (sampB overwrites patch — safe: barrier above.)
    {
        int p = lane >> 2, c16 = lane & 3;
        const __hip_bfloat16* xb16 = xBp + (size_t)b * (130 * 130 * 64) + c16 * 16 + 131 * 64;
        if      (wv == 0) sample_taps16<0, 2>(xb16, offL, sampB, h, w0, p, c16);
        else if (wv == 1) sample_taps16<2, 4>(xb16, offL, sampB, h, w0, p, c16);
        else if (wv == 2) sample_taps16<4, 6>(xb16, offL, sampB, h, w0, p, c16);
        else {            sample_taps16<6, 8>(xb16, offL, sampB, h, w0, p, c16);
                          sample_taps16<8, 9>(xb16, offL, sampB, h, w0, p, c16); }
    }
    __syncthreads();

    // ---- phase 5: einsum via MFMA; wave wv = o-tile; 18 K-steps
    {
        int n = lane & 15, q = lane >> 4;
        int arow = n * 40 + q * 8;          // A: m = pixel = lane&15
        const short8* BwW = (const short8*)Wb + (wv * 18) * 64 + lane;
        f32x4 acc = {0.f, 0.f, 0.f, 0.f};
#pragma unroll
        for (int s = 0; s < 18; ++s) {
            const short8 a = *(const short8*)&sampB[s * 640 + arow];
            acc = __builtin_amdgcn_mfma_f32_16x16x32_bf16(a, BwW[s * 64], acc, 0, 0, 0);
        }
        int o = wv * 16 + n;
        float bo = bias[o];
        // C/D: col = o, row m = q*4+reg = pixel -> w = w0 + q*4 + reg
        float4 st = {acc[0] + bo, acc[1] + bo, acc[2] + bo, acc[3] + bo};
        *(float4*)&out[(((size_t)b * 64 + o) * 128 + h) * 128 + w0 + q * 4] = st;
    }
}

// ---------------------------------------------------------------- launch
extern "C" void kernel_launch(void* const* d_in, const int* in_sizes, int n_in,
                              void* d_out, int out_size, void* d_ws, size_t ws_size,
                              hipStream_t stream) {
    const float* x        = (const float*)d_in[0];
    const float* offset_w = (const float*)d_in[1];
    const float* offset_b = (const float*)d_in[2];
    const float* weight   = (const float*)d_in[3];
    const float* bias     = (const float*)d_in[4];
    char* ws = (char*)d_ws;
    __hip_bfloat16* xBp = (__hip_bfloat16*)ws;                          // 8,652,800 B
    __hip_bfloat16* Wb  = (__hip_bfloat16*)(ws + 8652800);              // 73,728 B
    __hip_bfloat16* OWb = (__hip_bfloat16*)(ws + 8652800 + 73728);      // 36,864 B
    float* outp = (float*)d_out;

    hipLaunchKernelGGL(prep_transpose_kernel, dim3(736),  dim3(256), 0, stream,
                       x, xBp, offset_w, weight, Wb, OWb);
    hipLaunchKernelGGL(deform_kernel,         dim3(4096), dim3(256), 0, stream,
                       xBp, Wb, OWb, offset_b, bias, outp);
}

// Round 11
// 104.441 us; speedup vs baseline: 1.0167x; 1.0167x over previous
//
#include <hip/hip_runtime.h>
#include <hip/hip_bf16.h>

// B=4, C=64, O=64, H=W=128, K=3, KK=9, PAD=1
// MFMA 16x16x32 bf16: A[m=lane&15][k=(lane>>4)*8+j], B[n=lane&15][k=...],
// C/D: col(n)=lane&15, row(m)=(lane>>4)*4+reg
// kappa = s*32 + q*8 + j  ->  tap = s>>1, c = (s&1)*32 + q*8 + j
//
// Round-11: LDS bank-conflict fix (r7 counter: 1.87M conflict cycles/dispatch).
//   sampB row stride 40 -> 36 shorts (72 B = 18 banks; 18n mod 32 injective for
//   n=0..15 -> conflict-free phase-5 reads / phase-4 stores; was 20 banks, 2-way).
//   patch stride 80 -> 88 shorts (176 B; phase-2 read banks 12*pix mod 32 = 2-way,
//   was 8*pix mod 32 = 4-way).
// Sampling partition: r9's (best measured) 8 lanes/px, taps 4/5 over wave pairs,
// all corner loads batched (r8/r9: latency fix, -6 us cumulative).
//
// ws layout (bytes):
//   xBp  [4][130][130][64] bf16 : ofs 0        (8.65 MB zero-halo padded NHWC bf16 of x)
//   Wb   [4][18][64][8]   bf16  : ofs 8652800  (deform weight B-frags)
//   OWb  [2][18][64][8]   bf16  : ofs 8726528  (offset_w B-frags)

typedef short short8 __attribute__((ext_vector_type(8)));
typedef float f32x4 __attribute__((ext_vector_type(4)));

#define SROW 36            // shorts per (s,p) row of sampB (32 data + 4 pad)
#define PROW 88            // shorts per pixel row of patch (64 data + 24 pad)

static __device__ inline short bf16s(float f) {
    __hip_bfloat16 h = __float2bfloat16(f);
    return *(short*)&h;
}
static __device__ inline float lo2f(unsigned u) { return __uint_as_float(u << 16); }
static __device__ inline float hi2f(unsigned u) { return __uint_as_float(u & 0xffff0000u); }

// ---------------------------------------------------------------- fused prep + NCHW->padded-NHWC-bf16
// grid = 736: blocks 0..519 transpose (XCD-swizzled), 520..735 prep fragment packing.
__global__ void prep_transpose_kernel(const float* __restrict__ x,
                                      __hip_bfloat16* __restrict__ xBp,
                                      const float* __restrict__ offset_w, // [18][64][9]
                                      const float* __restrict__ weight,   // [64][64][9]
                                      __hip_bfloat16* __restrict__ Wb,    // [4][18][64][8]
                                      __hip_bfloat16* __restrict__ OWb)   // [2][18][64][8]
{
    __shared__ __align__(16) float lds[128 * 65];
    int raw = blockIdx.x;
    int t = threadIdx.x;

    if (raw >= 520) {                   // ---- prep path
        int id = (raw - 520) * 256 + t;
        if (id < 36864) {
            int j    = id & 7;
            int lane = (id >> 3) & 63;
            int id3  = id >> 9;
            int s    = id3 % 18;
            int otile = id3 / 18;
            int n = lane & 15, q = lane >> 4;
            int kap = s * 32 + q * 8 + j;      // kappa = k*64 + c
            int k = kap >> 6, c = kap & 63;
            int o = otile * 16 + n;
            Wb[id] = __float2bfloat16(weight[(o * 64 + c) * 9 + k]);
        }
        int id2 = id - 36864;
        if (id2 >= 0 && id2 < 18432) {
            int j    = id2 & 7;
            int lane = (id2 >> 3) & 63;
            int id3  = id2 >> 9;
            int s    = id3 % 18;
            int ntile = id3 / 18;
            int n = lane & 15, q = lane >> 4;
            int kap = s * 32 + q * 8 + j;
            int k = kap >> 6, c = kap & 63;
            int o = ntile * 16 + n;
            float v = (o < 18) ? offset_w[(o * 64 + c) * 9 + k] : 0.0f;
            OWb[id2] = __float2bfloat16(v);
        }
        return;
    }

    // ---- transpose path (XCD swizzle: 520 = 8*65)
    int blk = (raw & 7) * 65 + (raw >> 3);   // b*130 + r
    int b = blk / 130, r = blk - b * 130;
    unsigned* rowp = (unsigned*)(xBp + (size_t)(b * 130 + r) * 130 * 64); // 4160 dwords per row
    if (r == 0 || r == 129) {           // full zero row (halo)
        uint4 z = {0u, 0u, 0u, 0u};
        for (int i = 0; i < 5; ++i) {
            int e = i * 256 + t;
            if (e < 1040) ((uint4*)rowp)[e] = z;
        }
        return;
    }
    int h = r - 1;
    // load 64c x 128w floats as float4 along w: 2048 float4, 8 per thread
    const float4* x4 = (const float4*)x;
    size_t base4 = (size_t)b * 262144 + (size_t)h * 32;  // + c*4096 + w4
#pragma unroll
    for (int i = 0; i < 8; ++i) {
        int idx = i * 256 + t;          // idx = c*32 + w4
        int c = idx >> 5, w4 = idx & 31;
        float4 v = x4[base4 + (size_t)c * 4096 + w4];
        int wb = w4 * 4;
        lds[(wb + 0) * 65 + c] = v.x;
        lds[(wb + 1) * 65 + c] = v.y;
        lds[(wb + 2) * 65 + c] = v.z;
        lds[(wb + 3) * 65 + c] = v.w;
    }
    __syncthreads();
    unsigned* dst = rowp + 32;          // col 1 (each col = 64 shorts = 32 dwords)
    for (int i = 0; i < 16; ++i) {
        int L = i * 256 + t;            // L = ww*32 + c2
        int ww = L >> 5, c2 = L & 31;
        float f0 = lds[ww * 65 + c2 * 2];
        float f1 = lds[ww * 65 + c2 * 2 + 1];
        unsigned pk = ((unsigned)bf16s(f0) & 0xffffu) | ((unsigned)bf16s(f1) << 16);
        dst[L] = pk;
    }
    if (t < 64) {                       // zero halo cols 0 and 129
        int col = (t >> 5) * 129;
        rowp[col * 32 + (t & 31)] = 0u;
    }
}

// ---------------------------------------------------------------- phase-4 sampling helper
// Lane owns 8 channels (c8*8..c8*8+7) of pixel p; taps K0..K1-1.
// Loop 1 issues ALL corner loads (statically-indexed reg arrays -> no scratch),
// loop 2 consumes. Zero-halo padding: clamp to [-1,128]; halo reads return 0.
template<int K0, int K1>
static __device__ inline void sample_taps(const __hip_bfloat16* __restrict__ xb8,
                                          const float* __restrict__ offL,
                                          short* __restrict__ sampB,
                                          int h, int w0, int p, int c8)
{
    constexpr int NT = K1 - K0;
    float wa[NT], wb_[NT], wc[NT], wd[NT];
    uint4 r0[NT], r1[NT], r2[NT], r3[NT];
#pragma unroll
    for (int i = 0; i < NT; ++i) {
        int k = K0 + i;
        float offy = offL[(2 * k) * 16 + p];
        float offx = offL[(2 * k + 1) * 16 + p];
        float py = (float)(h - 1 + (k / 3)) + offy;
        float px = (float)(w0 + p - 1 + (k % 3)) + offx;
        float y0f = floorf(py), x0f = floorf(px);
        float wy1 = py - y0f, wx1 = px - x0f;
        float wy0 = 1.0f - wy1, wx0 = 1.0f - wx1;
        int iy = (int)y0f, ix = (int)x0f;
        int iy0 = min(max(iy, -1), 128);
        int ix0 = min(max(ix, -1), 128);
        int iy1 = min(max(iy + 1, -1), 128);
        int ix1 = min(max(ix + 1, -1), 128);
        int rb0 = iy0 * 130, rb1 = iy1 * 130;
        r0[i] = *(const uint4*)(xb8 + (rb0 + ix0) * 64);
        r1[i] = *(const uint4*)(xb8 + (rb0 + ix1) * 64);
        r2[i] = *(const uint4*)(xb8 + (rb1 + ix0) * 64);
        r3[i] = *(const uint4*)(xb8 + (rb1 + ix1) * 64);
        wa[i] = wy0 * wx0;
        wb_[i] = wy0 * wx1;
        wc[i] = wy1 * wx0;
        wd[i] = wy1 * wx1;
    }
#pragma unroll
    for (int i = 0; i < NT; ++i) {
        int k = K0 + i;
        short8 pk;
#define SAMP1(idx, comp, EXT) { \
            float sv = fmaf(wd[i], EXT(r3[i].comp), fmaf(wc[i], EXT(r2[i].comp), \
                       fmaf(wb_[i], EXT(r1[i].comp), wa[i] * EXT(r0[i].comp)))); \
            pk[idx] = bf16s(sv); }
        SAMP1(0, x, lo2f) SAMP1(1, x, hi2f)
        SAMP1(2, y, lo2f) SAMP1(3, y, hi2f)
        SAMP1(4, z, lo2f) SAMP1(5, z, hi2f)
        SAMP1(6, w, lo2f) SAMP1(7, w, hi2f)
#undef SAMP1
        int s = 2 * k + (c8 >> 2);
        *(short8*)&sampB[(s * 16 + p) * SROW + (c8 & 3) * 8] = pk;
    }
}

// ---------------------------------------------------------------- fused offconv + sampling + deform conv
// block = 16x1 row tile; 4 waves; grid = 4096 (XCD-swizzled: 8*512)
// LDS = sampB 20736 (patch[54][88] aliases its head) + offL 1152 = 21888 B
// launch_bounds(256,4): VGPR cap 128 so the full gather tap-batch stays in flight.
__global__ __launch_bounds__(256, 4) void deform_kernel(
    const __hip_bfloat16* __restrict__ xBp, // [4][130][130][64] padded NHWC bf16
    const __hip_bfloat16* __restrict__ Wb,  // [4][18][64][8]
    const __hip_bfloat16* __restrict__ OWb, // [2][18][64][8]
    const float* __restrict__ offset_b,     // [18]
    const float* __restrict__ bias,         // [64]
    float* __restrict__ out)                // [4][64][128][128] NCHW
{
    __shared__ __align__(16) short sampB[18 * 16 * SROW];  // 20736 B
    __shared__ __align__(16) float offL[288];              // [o][p] (separate — NOT aliased)

    int t = threadIdx.x, wv = t >> 6, lane = t & 63;
    int bid = (blockIdx.x & 7) * 512 + (blockIdx.x >> 3); // XCD swizzle: contiguous (b,h) per XCD
    int b  = bid >> 10;
    int h  = (bid >> 3) & 127;
    int w0 = (bid & 7) << 4;

    short* patch = sampB;            // [54 px][PROW shorts]; px = row*18+col
                                     // rows = padded h..h+2, cols = padded w0..w0+17

    // ---- phase 1: stage 3x18x64 patch bf16 — branchless (halo is pre-zeroed), 16-B chunks
    {
#pragma unroll
        for (int i = 0; i < 2; ++i) {
            int e = i * 256 + t;            // 54*8 = 432 chunks of 16 B
            if (e < 432) {
                int px = e >> 3, part = e & 7;
                int row = px / 18, col = px - row * 18;
                const uint4* src = (const uint4*)(xBp +
                    ((size_t)((b * 130 + h + row) * 130) + w0 + col) * 64 + part * 8);
                *(uint4*)&patch[px * PROW + part * 8] = *src;
            }
        }
    }
    __syncthreads();

    // ---- phase 2: offset conv via MFMA (waves 0,1; o = wv*16+n; pixel p = q*4+reg)
    if (wv < 2) {
        int n = lane & 15, q = lane >> 4;
        const short8* Bw = (const short8*)OWb + (wv * 18) * 64 + lane;
        f32x4 acc = {0.f, 0.f, 0.f, 0.f};
#pragma unroll
        for (int s = 0; s < 18; ++s) {
            int k = s >> 1;
            int ky = k / 3, kx = k - ky * 3;
            int pix = ky * 18 + n + kx;
            const short8 a = *(const short8*)&patch[pix * PROW + (s & 1) * 32 + q * 8];
            acc = __builtin_amdgcn_mfma_f32_16x16x32_bf16(a, Bw[s * 64], acc, 0, 0, 0);
        }
        int o = wv * 16 + n;
        if (o < 18) {
            float bo = offset_b[o];
#pragma unroll
            for (int r = 0; r < 4; ++r)
                offL[o * 16 + q * 4 + r] = acc[r] + bo;
        }
    }
    __syncthreads();

    // ---- phase 4: sampling; 8 lanes/pixel (lane owns 8 channels), taps split over wave pairs
    // waves 0,1: taps 0..3; waves 2,3: taps 4..8. p = (wv&1)*8 + (lane>>3).
    // (sampB overwrites patch — safe: patch last read in phase 2, barrier between.)
    {
        int g8 = lane >> 3, c8 = lane & 7;
        int p = (wv & 1) * 8 + g8;
        const __hip_bfloat16* xb8 = xBp + (size_t)b * (130 * 130 * 64) + c8 * 8 + 131 * 64;
        if (wv < 2) sample_taps<0, 4>(xb8, offL, sampB, h, w0, p, c8);
        else        sample_taps<4, 9>(xb8, offL, sampB, h, w0, p, c8);
    }
    __syncthreads();

    // ---- phase 5: einsum via MFMA; wave wv = o-tile; 18 K-steps
    {
        int n = lane & 15, q = lane >> 4;
        int arow = n * SROW + q * 8;        // A: m = pixel = lane&15
        const short8* BwW = (const short8*)Wb + (wv * 18) * 64 + lane;
        f32x4 acc = {0.f, 0.f, 0.f, 0.f};
#pragma unroll
        for (int s = 0; s < 18; ++s) {
            const short8 a = *(const short8*)&sampB[s * (16 * SROW) + arow];
            acc = __builtin_amdgcn_mfma_f32_16x16x32_bf16(a, BwW[s * 64], acc, 0, 0, 0);
        }
        int o = wv * 16 + n;
        float bo = bias[o];
        // C/D: col = o, row m = q*4+reg = pixel -> w = w0 + q*4 + reg
        float4 st = {acc[0] + bo, acc[1] + bo, acc[2] + bo, acc[3] + bo};
        *(float4*)&out[(((size_t)b * 64 + o) * 128 + h) * 128 + w0 + q * 4] = st;
    }
}

// ---------------------------------------------------------------- launch
extern "C" void kernel_launch(void* const* d_in, const int* in_sizes, int n_in,
                              void* d_out, int out_size, void* d_ws, size_t ws_size,
                              hipStream_t stream) {
    const float* x        = (const float*)d_in[0];
    const float* offset_w = (const float*)d_in[1];
    const float* offset_b = (const float*)d_in[2];
    const float* weight   = (const float*)d_in[3];
    const float* bias     = (const float*)d_in[4];
    char* ws = (char*)d_ws;
    __hip_bfloat16* xBp = (__hip_bfloat16*)ws;                          // 8,652,800 B
    __hip_bfloat16* Wb  = (__hip_bfloat16*)(ws + 8652800);              // 73,728 B
    __hip_bfloat16* OWb = (__hip_bfloat16*)(ws + 8652800 + 73728);      // 36,864 B
    float* outp = (float*)d_out;

    hipLaunchKernelGGL(prep_transpose_kernel, dim3(736),  dim3(256), 0, stream,
                       x, xBp, offset_w, weight, Wb, OWb);
    hipLaunchKernelGGL(deform_kernel,         dim3(4096), dim3(256), 0, stream,
                       xBp, Wb, OWb, offset_b, bias, outp);
}